// Round 9
// baseline (1355.679 us; speedup 1.0000x reference)
//
#include <hip/hip_runtime.h>
#include <hip/hip_bf16.h>

#define IN_DIM 2048
#define HID    1024
#define ATT    40
#define BATCH  4096

#define BM 128
#define BN 128
#define BK 64

typedef unsigned short u16;
typedef __attribute__((ext_vector_type(8))) __bf16 bf16x8;
typedef __attribute__((ext_vector_type(4))) float  f32x4;

struct alignas(8)  u16x4 { u16 a, b, c, d; };
struct alignas(16) u16x8 { u16x4 lo, hi; };

__device__ __forceinline__ u16 f2bf(float f) {
    unsigned int u = __float_as_uint(f);
    unsigned int r = (u + 0x7fffu + ((u >> 16) & 1u)) >> 16;   // RNE
    return (u16)r;
}
// RNE via HW cvt (v_cvt_pk_bf16_f32) — bit-identical to f2bf on non-NaN input
__device__ __forceinline__ u16 f2bf_hw(float f) {
    __bf16 h = (__bf16)f;
    return __builtin_bit_cast(u16, h);
}
__device__ __forceinline__ float f4get(const float4& v, int j) {
    return reinterpret_cast<const float*>(&v)[j];
}

// async global->LDS 16B/lane; LDS dest is wave-uniform base + lane*16
__device__ __forceinline__ void load16_to_lds(const void* g, void* l) {
    __builtin_amdgcn_global_load_lds(
        (const __attribute__((address_space(1))) unsigned int*)(uintptr_t)g,
        (__attribute__((address_space(3))) unsigned int*)(uintptr_t)l,
        16, 0, 0);
}

// ---------------- x fp32 -> bf16 (same layout) ----------------
__global__ void convert_x(const float* __restrict__ x, u16* __restrict__ xb) {
    int i = (blockIdx.x * 256 + threadIdx.x) * 4;
    float4 v = *(const float4*)(x + i);
    u16x4 o = { f2bf(v.x), f2bf(v.y), f2bf(v.z), f2bf(v.w) };
    *(u16x4*)(xb + i) = o;
}

// ---------------- fused GEMM + bias + gelu + W2-dot (atomic partials) ------------
// B is staged DIRECTLY from fp32 W1 [a][K][N] (no transpose/convert pass):
// per tile each thread loads 8 float4 (coalesced 512B rows), converts RNE,
// 4x4-transposes in registers, ds_writes k-contig u16x4 chunks into the same
// LDS layout the (verified) fragment reads use. B swizzle key widened to
// (n&7)^((n>>3)&7) on BOTH write and read so 16-lane write groups are 2-way
// (free); A path (global_load_lds + (row&7) key) untouched.
__global__ __launch_bounds__(256, 3) void gemm_fused(
    const u16*  __restrict__ xb,   // [4096][2048] bf16
    const float* __restrict__ W1,  // [40][2048][1024] fp32 (native layout)
    const float* __restrict__ b1,  // [40][1024]
    const float* __restrict__ w2,  // [40][1024]
    float* __restrict__ partial)   // [4096][40], pre-zeroed
{
    __shared__ __align__(16) u16 smem[2 * BM * BK];   // A:[0,8192) B:[8192,16384) u16
    const int a  = blockIdx.z;
    const int m0 = blockIdx.x * BM;
    const int n0 = blockIdx.y * BN;

    const int tid  = threadIdx.x;
    const int w    = tid >> 6;
    const int l    = tid & 63;
    const int quad = l >> 4;
    const int lr   = l & 15;
    const int wm   = (w >> 1) * 64;
    const int wn   = (w & 1) * 64;

    // ---- A staging offsets (global elements, pre-swizzled source) ----
    int offG[4];
    #pragma unroll
    for (int j = 0; j < 4; ++j) {
        int p   = j * 256 + tid;
        int row = p >> 3;
        int kc  = (p & 7) ^ (row & 7);
        offG[j] = row * IN_DIM + kc * 8;
    }
    // ---- B staging: thread owns rows 8kq..8kq+7, cols 4nn..4nn+3 of the tile ----
    const int nn = tid & 31;
    const int kq = tid >> 5;
    int offWB[4];
    #pragma unroll
    for (int j = 0; j < 4; ++j) {
        int n  = 4 * nn + j;
        int sn = (n & 7) ^ ((n >> 3) & 7);
        offWB[j] = BM * BK + n * BK + ((kq ^ sn)) * 8;
    }
    // ---- LDS read offsets (u16 elements) ----
    int offLA[2][4], offLB[2][4];
    #pragma unroll
    for (int ks = 0; ks < 2; ++ks)
        #pragma unroll
        for (int f = 0; f < 4; ++f) {
            int rowA = wm + f * 16 + lr;
            int kcA  = (ks * 4 + quad) ^ (rowA & 7);
            offLA[ks][f] = rowA * BK + kcA * 8;
            int rowB = wn + f * 16 + lr;
            int sB   = (rowB & 7) ^ ((rowB >> 3) & 7);
            int kcB  = (ks * 4 + quad) ^ sB;
            offLB[ks][f] = BM * BK + rowB * BK + kcB * 8;
        }

    const u16*   Abase = xb + (size_t)m0 * IN_DIM;
    const float* Bbase = W1 + (size_t)a * ((size_t)IN_DIM * HID) + n0;

    f32x4 acc[4][4];
    #pragma unroll
    for (int i = 0; i < 4; ++i)
        #pragma unroll
        for (int j = 0; j < 4; ++j)
            acc[i][j] = (f32x4){0.f, 0.f, 0.f, 0.f};

    for (int k0 = 0; k0 < IN_DIM; k0 += BK) {
        // A: async global->LDS (issue first, flies during B's reg staging)
        const u16* Ak = Abase + k0;
        #pragma unroll
        for (int j = 0; j < 4; ++j)
            load16_to_lds(Ak + offG[j], &smem[(j * 256 + w * 64) * 8]);
        // B: fp32 load -> cvt -> 4x4 reg transpose -> k-contig LDS writes
        const float* Bk = Bbase + (size_t)(k0 + 8 * kq) * HID + 4 * nn;
        #pragma unroll
        for (int h = 0; h < 2; ++h) {
            float4 v0 = *(const float4*)(Bk + (4 * h + 0) * HID);
            float4 v1 = *(const float4*)(Bk + (4 * h + 1) * HID);
            float4 v2 = *(const float4*)(Bk + (4 * h + 2) * HID);
            float4 v3 = *(const float4*)(Bk + (4 * h + 3) * HID);
            #pragma unroll
            for (int j = 0; j < 4; ++j) {
                u16x4 o = { f2bf_hw(f4get(v0, j)), f2bf_hw(f4get(v1, j)),
                            f2bf_hw(f4get(v2, j)), f2bf_hw(f4get(v3, j)) };
                *(u16x4*)&smem[offWB[j] + h * 4] = o;
            }
        }
        __syncthreads();

        #pragma unroll
        for (int ks = 0; ks < 2; ++ks) {
            bf16x8 af[4], bfr[4];
            #pragma unroll
            for (int f = 0; f < 4; ++f) af[f]  = *(const bf16x8*)&smem[offLA[ks][f]];
            #pragma unroll
            for (int f = 0; f < 4; ++f) bfr[f] = *(const bf16x8*)&smem[offLB[ks][f]];
            #pragma unroll
            for (int fm = 0; fm < 4; ++fm)
                #pragma unroll
                for (int fn = 0; fn < 4; ++fn)
                    acc[fm][fn] = __builtin_amdgcn_mfma_f32_16x16x32_bf16(
                        af[fm], bfr[fn], acc[fm][fn], 0, 0, 0);
        }
        __syncthreads();
    }

    // ---- epilogue: +b1, exact gelu, *W2, reduce over this tile's 128 cols ----
    float b1v[4], w2v[4];
    #pragma unroll
    for (int fn = 0; fn < 4; ++fn) {
        int col = n0 + wn + fn * 16 + lr;
        b1v[fn] = b1[a * HID + col];
        w2v[fn] = w2[a * HID + col];
    }
    #pragma unroll
    for (int fm = 0; fm < 4; ++fm) {
        #pragma unroll
        for (int r = 0; r < 4; ++r) {
            float s = 0.f;
            #pragma unroll
            for (int fn = 0; fn < 4; ++fn) {
                float z = acc[fm][fn][r] + b1v[fn];
                float g = 0.5f * z * (1.0f + erff(z * 0.70710678118654752f));
                s += g * w2v[fn];
            }
            s += __shfl_xor(s, 1, 64);
            s += __shfl_xor(s, 2, 64);
            s += __shfl_xor(s, 4, 64);
            s += __shfl_xor(s, 8, 64);
            if (lr == 0) {
                int grow = m0 + wm + fm * 16 + quad * 4 + r;
                atomicAdd(&partial[grow * ATT + a], s);
            }
        }
    }
}

// ---------------- sigmoid(partial + b2) -> out ----------------
__global__ void finish_kernel(const float* __restrict__ partial,
                              const float* __restrict__ b2,
                              float* __restrict__ out, int n) {
    int i = blockIdx.x * 256 + threadIdx.x;
    if (i < n) {
        float z = partial[i] + b2[i % ATT];
        out[i] = 1.0f / (1.0f + expf(-z));
    }
}

extern "C" void kernel_launch(void* const* d_in, const int* in_sizes, int n_in,
                              void* d_out, int out_size, void* d_ws, size_t ws_size,
                              hipStream_t stream) {
    const float* x  = (const float*)d_in[0];
    const float* W1 = (const float*)d_in[1];
    const float* b1 = (const float*)d_in[2];
    const float* W2 = (const float*)d_in[3];
    const float* b2 = (const float*)d_in[4];
    float* out = (float*)d_out;

    char* ws = (char*)d_ws;
    float* partial = (float*)ws;                                   // 640 KB
    u16*   xb      = (u16*)(ws + 655360);                          // 16 MB

    hipMemsetAsync(partial, 0, (size_t)BATCH * ATT * sizeof(float), stream);
    convert_x<<<dim3(BATCH * IN_DIM / (256 * 4)), dim3(256), 0, stream>>>(x, xb);
    gemm_fused<<<dim3(BATCH / BM, HID / BN, ATT), dim3(256), 0, stream>>>(
        xb, W1, b1, W2, partial);
    finish_kernel<<<dim3((BATCH * ATT + 255) / 256), dim3(256), 0, stream>>>(
        partial, b2, out, BATCH * ATT);
}